// Round 1
// baseline (173.559 us; speedup 1.0000x reference)
//
#include <hip/hip_runtime.h>

// NaiveFourierKANLayer: y = cos-features @ W0^T + sin-features @ W1^T + bias
// N=32768, INPUTDIM=64, OUTDIM=256, GRIDSIZE=32 -> GEMM M=32768, N=256, K=4096
//
// Strategy:
//  - Pre-pass (wconv): gather fouriercoeffs (2,256,64,32) fp32 into B^T layout
//    Wr[o][i*64 + c*32 + g] as bf16 (2 MB) in d_ws. Runs every launch (ws is
//    re-poisoned by the harness).
//  - Main GEMM (m97 structure): 128x128 tile, 256 threads, BK=64 = one input
//    dim's [cos g=1..32 | sin g=1..32]. A-tile computed on the fly with the
//    angle-addition recurrence from 4 hardware v_sin/v_cos (revolutions),
//    written bf16 into an XOR-swizzled LDS tile. B-tile staged with
//    global_load_lds width=16 (lane-contiguous, unpadded). 16x16x32 bf16 MFMA,
//    4x4 accumulators per wave, verified C/D layout col=lane&15,
//    row=(lane>>4)*4+reg.

#define IDIM 64
#define ODIM 256
#define KDIM 4096

typedef __attribute__((ext_vector_type(8))) unsigned short ushort8_t;
typedef __bf16 bf16x8 __attribute__((ext_vector_type(8)));
typedef float floatx4 __attribute__((ext_vector_type(4)));

__device__ __forceinline__ unsigned short f2bf_rne(float f) {
  unsigned int u = __float_as_uint(f);
  return (unsigned short)((u + 0x7FFFu + ((u >> 16) & 1u)) >> 16);
}

// cheap round-half-up (2 VALU ops) -- bias negligible vs 2% tolerance
__device__ __forceinline__ unsigned short f2bf_fast(float f) {
  unsigned int u = __float_as_uint(f);
  return (unsigned short)((u + 0x8000u) >> 16);
}

__device__ __forceinline__ void gl_lds16(const void* g, void* l) {
  __builtin_amdgcn_global_load_lds(
      (__attribute__((address_space(1))) void*)g,
      (__attribute__((address_space(3))) void*)l, 16, 0, 0);
}

// ---- weight gather+convert: fc(2,256,64,32) fp32 -> Wr(256,4096) bf16 ----
__global__ void __launch_bounds__(256) wconv(const float* __restrict__ fc,
                                             unsigned short* __restrict__ Wr) {
  int e = (blockIdx.x * 256 + threadIdx.x) << 2;  // element idx, 4 per thread
  int o = e >> 12;
  int k = e & 4095;
  int i = k >> 6;
  int c = (k >> 5) & 1;
  int g = k & 31;  // multiple of 4
  const float4 v = *(const float4*)(fc + ((size_t)c << 19) + o * 2048 + i * 32 + g);
  ushort4 r;
  r.x = f2bf_rne(v.x);
  r.y = f2bf_rne(v.y);
  r.z = f2bf_rne(v.z);
  r.w = f2bf_rne(v.w);
  *(ushort4*)(Wr + e) = r;
}

// ---- fused feature-gen + GEMM ----
__global__ void __launch_bounds__(256) fkan_gemm(const float* __restrict__ X,
                                                 const unsigned short* __restrict__ Wr,
                                                 const float* __restrict__ bias,
                                                 float* __restrict__ out) {
  __shared__ __align__(16) unsigned short As[128 * 64];  // [m][k] XOR-swizzled
  __shared__ __align__(16) unsigned short Bs[128 * 64];  // [n][k] row-major (B^T)

  const int t = threadIdx.x;
  const int wv = t >> 6;        // wave 0..3
  const int ln = t & 63;
  const int lm = ln & 15;
  const int quad = ln >> 4;
  const int wm = wv >> 1;       // wave m-half
  const int wn = wv & 1;        // wave n-half
  const int m0 = blockIdx.y * 128;
  const int n0 = blockIdx.x * 128;

  // A-staging role: one row per thread, half of g-range per p
  const int arow = t & 127;
  const int p = t >> 7;  // 0: g=1..16, 1: g=17..32
  const float gstart = (float)(16 * p + 1);

  floatx4 acc[4][4];
#pragma unroll
  for (int a = 0; a < 4; ++a)
#pragma unroll
    for (int b = 0; b < 4; ++b)
      acc[a][b] = (floatx4){0.0f, 0.0f, 0.0f, 0.0f};

  const float* xptr = X + (size_t)(m0 + arow) * IDIM;

  for (int kt = 0; kt < IDIM; ++kt) {
    // ---- A staging: Fourier features for input dim i = kt ----
    {
      float xv = xptr[kt];
      float u = xv * 0.15915494309189535f;  // revolutions
      float c1 = __builtin_amdgcn_cosf(u);  // cos(x)
      float s1 = __builtin_amdgcn_sinf(u);  // sin(x)
      float u0 = u * gstart;
      float cg = __builtin_amdgcn_cosf(u0);  // cos(gstart*x)
      float sg = __builtin_amdgcn_sinf(u0);
      union { unsigned short us[16]; ushort8_t v[2]; } cp, sp;
#pragma unroll
      for (int j = 0; j < 16; ++j) {
        cp.us[j] = f2bf_fast(cg);
        sp.us[j] = f2bf_fast(sg);
        float nc = cg * c1 - sg * s1;
        float ns = sg * c1 + cg * s1;
        cg = nc;
        sg = ns;
      }
      // swizzled write: 16B granule index = row*8 + (chunk ^ (row&7))
      ushort8_t* As8 = (ushort8_t*)As;
      int sw = arow & 7;
      int gb = arow * 8;
      As8[gb + ((2 * p) ^ sw)] = cp.v[0];      // cos k = p*16 + 0..7
      As8[gb + ((2 * p + 1) ^ sw)] = cp.v[1];  // cos k = p*16 + 8..15
      As8[gb + ((4 + 2 * p) ^ sw)] = sp.v[0];  // sin k = 32 + p*16 + 0..7
      As8[gb + ((5 + 2 * p) ^ sw)] = sp.v[1];
    }

    // ---- B staging: async global->LDS, 4 x 16B per thread ----
#pragma unroll
    for (int j = 0; j < 4; ++j) {
      int region = wv * 4 + j;             // 16 regions x 1KB = 16KB tile
      int rowB = region * 8 + (ln >> 3);   // local n row
      int koff = (ln & 7) * 8;             // bf16 elems within row
      const unsigned short* gsrc =
          Wr + (size_t)(n0 + rowB) * KDIM + kt * 64 + koff;
      gl_lds16(gsrc, Bs + region * 512);   // lane l lands at +l*16 bytes
    }

    __syncthreads();  // drains vmcnt (global_load_lds) + lgkmcnt (ds_write)

    // ---- MFMA: 2 k-halves x 16 MFMAs ----
#pragma unroll
    for (int kh = 0; kh < 2; ++kh) {
      bf16x8 af[4], bfr[4];
#pragma unroll
      for (int mt = 0; mt < 4; ++mt) {
        int r = wm * 64 + mt * 16 + lm;
        int gran = r * 8 + ((kh * 4 + quad) ^ (r & 7));
        af[mt] = __builtin_bit_cast(bf16x8, ((const ushort8_t*)As)[gran]);
      }
#pragma unroll
      for (int nt = 0; nt < 4; ++nt) {
        int n = wn * 64 + nt * 16 + lm;
        bfr[nt] = __builtin_bit_cast(
            bf16x8, *(const ushort8_t*)(Bs + n * 64 + kh * 32 + quad * 8));
      }
#pragma unroll
      for (int mt = 0; mt < 4; ++mt)
#pragma unroll
        for (int nt = 0; nt < 4; ++nt)
          acc[mt][nt] = __builtin_amdgcn_mfma_f32_16x16x32_bf16(
              af[mt], bfr[nt], acc[mt][nt], 0, 0, 0);
    }

    __syncthreads();
  }

  // ---- epilogue: C[row][col] = acc + bias, verified C/D layout ----
#pragma unroll
  for (int nt = 0; nt < 4; ++nt) {
    int col = n0 + wn * 64 + nt * 16 + lm;
    float bv = bias[col];
#pragma unroll
    for (int mt = 0; mt < 4; ++mt) {
      int rbase = m0 + wm * 64 + mt * 16 + quad * 4;
#pragma unroll
      for (int r = 0; r < 4; ++r)
        out[(size_t)(rbase + r) * ODIM + col] = acc[mt][nt][r] + bv;
    }
  }
}

extern "C" void kernel_launch(void* const* d_in, const int* in_sizes, int n_in,
                              void* d_out, int out_size, void* d_ws, size_t ws_size,
                              hipStream_t stream) {
  const float* x = (const float*)d_in[0];
  const float* fc = (const float*)d_in[1];
  const float* bias = (const float*)d_in[2];
  float* out = (float*)d_out;
  unsigned short* Wr = (unsigned short*)d_ws;  // needs 2 MB of workspace

  // weight gather/convert: 1M elems, 4/thread
  hipLaunchKernelGGL(wconv, dim3(1024), dim3(256), 0, stream, fc, Wr);
  // GEMM: grid = (O/128, M/128) = (2, 256), 256 threads
  hipLaunchKernelGGL(fkan_gemm, dim3(2, 256), dim3(256), 0, stream, x, Wr, bias, out);
}

// Round 2
// 160.648 us; speedup vs baseline: 1.0804x; 1.0804x over previous
//
#include <hip/hip_runtime.h>

// NaiveFourierKANLayer: y = cos-features @ W0^T + sin-features @ W1^T + bias
// N=32768, INPUTDIM=64, OUTDIM=256, GRIDSIZE=32 -> GEMM M=32768, N=256, K=4096
//
// R2 changes vs R1 (121.6 us gemm, MfmaUtil 24.5, VALUBusy 48, conflicts 1.26e7):
//  - B-tile LDS image XOR-swizzled via source-address permutation (global_load_lds
//    forces dst = base + lane*16, so we permute WHICH granule each lane fetches).
//    Kills the 16-lane bank-group collision on B ds_read_b128.
//  - Feature gen: two packed-f32 chains (even/odd g, step 2x) -> v_pk_fma_f32
//    eligible; bf16 pair-pack in 1 inst (v_cvt_pk_bf16_f32 if available, else
//    add+add+v_perm round-half-up). ~1.9 VALU/feature vs ~3.5.
//  - Async B fills issued BEFORE the feature chain (latency hides under VALU).

#define IDIM 64
#define ODIM 256
#define KDIM 4096

typedef __attribute__((ext_vector_type(8))) unsigned short ushort8_t;
typedef __bf16 bf16x8 __attribute__((ext_vector_type(8)));
typedef float floatx4 __attribute__((ext_vector_type(4)));
typedef float floatx2 __attribute__((ext_vector_type(2)));
typedef unsigned int uintx4 __attribute__((ext_vector_type(4)));

__device__ __forceinline__ unsigned short f2bf_rne(float f) {
  unsigned int u = __float_as_uint(f);
  return (unsigned short)((u + 0x7FFFu + ((u >> 16) & 1u)) >> 16);
}

// pack two fp32 -> packed bf16 pair (lo = a, hi = b)
#if __has_builtin(__builtin_amdgcn_cvt_pk_bf16_f32)
__device__ __forceinline__ unsigned int pack2bf(float a, float b) {
  auto v = __builtin_amdgcn_cvt_pk_bf16_f32(a, b);
  unsigned int r;
  __builtin_memcpy(&r, &v, 4);
  return r;
}
#else
__device__ __forceinline__ unsigned int pack2bf(float a, float b) {
  unsigned int ua = __float_as_uint(a) + 0x8000u;  // round-half-up
  unsigned int ub = __float_as_uint(b) + 0x8000u;
  return __builtin_amdgcn_perm(ub, ua, 0x07060302u);  // {hi16(b),hi16(a)}
}
#endif

__device__ __forceinline__ void gl_lds16(const void* g, void* l) {
  __builtin_amdgcn_global_load_lds(
      (__attribute__((address_space(1))) void*)g,
      (__attribute__((address_space(3))) void*)l, 16, 0, 0);
}

// ---- weight gather+convert: fc(2,256,64,32) fp32 -> Wr(256,4096) bf16 ----
__global__ void __launch_bounds__(256) wconv(const float* __restrict__ fc,
                                             unsigned short* __restrict__ Wr) {
  int e = (blockIdx.x * 256 + threadIdx.x) << 2;  // element idx, 4 per thread
  int o = e >> 12;
  int k = e & 4095;
  int i = k >> 6;
  int c = (k >> 5) & 1;
  int g = k & 31;  // multiple of 4
  const float4 v = *(const float4*)(fc + ((size_t)c << 19) + o * 2048 + i * 32 + g);
  ushort4 r;
  r.x = f2bf_rne(v.x);
  r.y = f2bf_rne(v.y);
  r.z = f2bf_rne(v.z);
  r.w = f2bf_rne(v.w);
  *(ushort4*)(Wr + e) = r;
}

// ---- fused feature-gen + GEMM ----
__global__ void __launch_bounds__(256) fkan_gemm(const float* __restrict__ X,
                                                 const unsigned short* __restrict__ Wr,
                                                 const float* __restrict__ bias,
                                                 float* __restrict__ out) {
  __shared__ __align__(16) unsigned short As[128 * 64];  // [m][k] XOR-swizzled
  __shared__ __align__(16) unsigned short Bs[128 * 64];  // [n][k] XOR-swizzled

  const int t = threadIdx.x;
  const int wv = t >> 6;        // wave 0..3
  const int ln = t & 63;
  const int lm = ln & 15;
  const int quad = ln >> 4;
  const int wm = wv >> 1;       // wave m-half
  const int wn = wv & 1;        // wave n-half
  const int m0 = blockIdx.y * 128;
  const int n0 = blockIdx.x * 128;

  // A-staging role: one row per thread, half of g-range per p
  const int arow = t & 127;
  const int p = t >> 7;  // 0: g=1..16, 1: g=17..32
  const float gstart = (float)(16 * p + 1);

  // B-staging: swizzled source so LDS image granule l holds
  // (row = l>>3, chunk = (l&7)^((l>>3)&7))
  const int brow_off = ln >> 3;
  const int bchunk = (ln & 7) ^ ((ln >> 3) & 7);

  floatx4 acc[4][4];
#pragma unroll
  for (int a = 0; a < 4; ++a)
#pragma unroll
    for (int b = 0; b < 4; ++b)
      acc[a][b] = (floatx4){0.0f, 0.0f, 0.0f, 0.0f};

  const float* xptr = X + (size_t)(m0 + arow) * IDIM;

  for (int kt = 0; kt < IDIM; ++kt) {
    // ---- B staging first: async global->LDS, latency hides under feature VALU
#pragma unroll
    for (int j = 0; j < 4; ++j) {
      int region = wv * 4 + j;             // 16 regions x 1KB
      int rowB = region * 8 + brow_off;
      const unsigned short* gsrc =
          Wr + (size_t)(n0 + rowB) * KDIM + kt * 64 + bchunk * 8;
      gl_lds16(gsrc, Bs + region * 512);   // lane l -> +l*16 bytes
    }

    // ---- A staging: Fourier features via two packed chains (even/odd g, step 2x)
    {
      float xv = xptr[kt];
      float u = xv * 0.15915494309189535f;  // revolutions
      float u0 = u * gstart;                // gstart*x
      float u1 = u0 + u;                    // (gstart+1)*x
      float u2 = u + u;                     // 2x
      float c2 = __builtin_amdgcn_cosf(u2);
      float s2 = __builtin_amdgcn_sinf(u2);
      floatx2 C = {__builtin_amdgcn_cosf(u0), __builtin_amdgcn_cosf(u1)};
      floatx2 S = {__builtin_amdgcn_sinf(u0), __builtin_amdgcn_sinf(u1)};
      floatx2 c2v = {c2, c2};
      floatx2 s2v = {s2, s2};
      unsigned int cpk[8], spk[8];
#pragma unroll
      for (int j = 0; j < 8; ++j) {
        cpk[j] = pack2bf(C.x, C.y);  // cos((gs+2j)x), cos((gs+2j+1)x)
        spk[j] = pack2bf(S.x, S.y);
        floatx2 t1 = C * s2v;
        floatx2 t2 = S * s2v;
        C = __builtin_elementwise_fma(C, c2v, -t2);
        S = __builtin_elementwise_fma(S, c2v, t1);
      }
      // swizzled granule writes: granule = row*8 + (chunk ^ (row&7))
      uintx4* As4 = (uintx4*)As;
      int sw = arow & 7;
      int gb = arow * 8;
      As4[gb + ((2 * p) ^ sw)] = (uintx4){cpk[0], cpk[1], cpk[2], cpk[3]};
      As4[gb + ((2 * p + 1) ^ sw)] = (uintx4){cpk[4], cpk[5], cpk[6], cpk[7]};
      As4[gb + ((4 + 2 * p) ^ sw)] = (uintx4){spk[0], spk[1], spk[2], spk[3]};
      As4[gb + ((5 + 2 * p) ^ sw)] = (uintx4){spk[4], spk[5], spk[6], spk[7]};
    }

    __syncthreads();  // drains vmcnt (global_load_lds) + lgkmcnt (ds_write)

    // ---- MFMA: 2 k-halves x 16 MFMAs ----
#pragma unroll
    for (int kh = 0; kh < 2; ++kh) {
      bf16x8 af[4], bfr[4];
#pragma unroll
      for (int mt = 0; mt < 4; ++mt) {
        int r = wm * 64 + mt * 16 + lm;
        int gran = r * 8 + ((kh * 4 + quad) ^ (r & 7));
        af[mt] = __builtin_bit_cast(bf16x8, ((const ushort8_t*)As)[gran]);
      }
#pragma unroll
      for (int nt = 0; nt < 4; ++nt) {
        int n = wn * 64 + nt * 16 + lm;
        int gran = n * 8 + ((kh * 4 + quad) ^ (n & 7));
        bfr[nt] = __builtin_bit_cast(bf16x8, ((const ushort8_t*)Bs)[gran]);
      }
#pragma unroll
      for (int mt = 0; mt < 4; ++mt)
#pragma unroll
        for (int nt = 0; nt < 4; ++nt)
          acc[mt][nt] = __builtin_amdgcn_mfma_f32_16x16x32_bf16(
              af[mt], bfr[nt], acc[mt][nt], 0, 0, 0);
    }

    __syncthreads();
  }

  // ---- epilogue: C[row][col] = acc + bias, verified C/D layout ----
#pragma unroll
  for (int nt = 0; nt < 4; ++nt) {
    int col = n0 + wn * 64 + nt * 16 + lm;
    float bv = bias[col];
#pragma unroll
    for (int mt = 0; mt < 4; ++mt) {
      int rbase = m0 + wm * 64 + mt * 16 + quad * 4;
#pragma unroll
      for (int r = 0; r < 4; ++r)
        out[(size_t)(rbase + r) * ODIM + col] = acc[mt][nt][r] + bv;
    }
  }
}

extern "C" void kernel_launch(void* const* d_in, const int* in_sizes, int n_in,
                              void* d_out, int out_size, void* d_ws, size_t ws_size,
                              hipStream_t stream) {
  const float* x = (const float*)d_in[0];
  const float* fc = (const float*)d_in[1];
  const float* bias = (const float*)d_in[2];
  float* out = (float*)d_out;
  unsigned short* Wr = (unsigned short*)d_ws;  // 2 MB of workspace

  hipLaunchKernelGGL(wconv, dim3(1024), dim3(256), 0, stream, fc, Wr);
  hipLaunchKernelGGL(fkan_gemm, dim3(2, 256), dim3(256), 0, stream, x, Wr, bias, out);
}